// Round 1
// baseline (9688.154 us; speedup 1.0000x reference)
//
#include <hip/hip_runtime.h>

#define BSZ 8192
#define DIM 128
#define MARGIN 0.3f
#define EPS 1e-8f

// ws layout (floats/uints, 4B slots):
// [0,      8192)  float  sq[i]      = ||e_i||^2
// [8192,  16384)  uint   maxpos[i]  (punned float, 0 = none)
// [16384, 24576)  uint   minneg[i]  (punned float, +inf = none)
// [24576]         float  loss_sum
// [24577]         uint   valid_count

__global__ __launch_bounds__(256) void k_sqnorm(const float* __restrict__ emb,
                                                float* __restrict__ sq,
                                                unsigned* __restrict__ maxp,
                                                unsigned* __restrict__ minn,
                                                float* __restrict__ sumcnt) {
    int row = blockIdx.x * 8 + (threadIdx.x >> 5);
    int lane = threadIdx.x & 31;
    const float4* e = (const float4*)(emb + (size_t)row * DIM);
    float4 v = e[lane];
    float s = v.x * v.x + v.y * v.y + v.z * v.z + v.w * v.w;
#pragma unroll
    for (int m = 16; m >= 1; m >>= 1) s += __shfl_xor(s, m);
    if (lane == 0) {
        sq[row] = s;
        maxp[row] = 0u;            // "no positive seen"
        minn[row] = 0x7F800000u;   // +inf = "no negative seen"
    }
    if (blockIdx.x == 0 && threadIdx.x == 0) {
        sumcnt[0] = 0.0f;
        ((unsigned*)sumcnt)[1] = 0u;
    }
}

// 64x64 tile of the Gram matrix per block-iteration; 256 threads = 16x16,
// each thread owns a 4x4 micro-tile: rows i = i0 + ty + 16r, cols j = j0 + tx + 16c.
__global__ __launch_bounds__(256) void k_main(const float* __restrict__ emb,
                                              const int* __restrict__ labels,
                                              const float* __restrict__ sq,
                                              unsigned* __restrict__ maxp,
                                              unsigned* __restrict__ minn) {
    __shared__ float Alds[64][132];   // +4 pad: 2-way conflicts only (free)
    __shared__ float Blds[64][132];
    __shared__ float sqj[64];
    __shared__ int   labj[64];

    const int tid = threadIdx.x;
    const int tx = tid & 15;
    const int ty = tid >> 4;
    const int i0 = blockIdx.x * 64;
    const int j0base = blockIdx.y * 512;   // 8192/16 = 512 cols per block

    // stage A (anchor) tile once: 64x128 floats, float4-coalesced
#pragma unroll
    for (int e = 0; e < 8; ++e) {
        int idx = e * 1024 + tid * 4;
        int row = idx >> 7, col = idx & 127;
        *(float4*)&Alds[row][col] =
            *(const float4*)&emb[(size_t)(i0 + row) * DIM + col];
    }

    int   irow[4]; float sqi[4]; int labi[4];
    float mp[4], mn[4];
#pragma unroll
    for (int r = 0; r < 4; ++r) {
        irow[r] = i0 + ty + 16 * r;
        sqi[r]  = sq[irow[r]];
        labi[r] = labels[irow[r]];
        mp[r] = 0.0f;
        mn[r] = __uint_as_float(0x7F800000u);
    }

    for (int t = 0; t < 8; ++t) {
        const int j0 = j0base + t * 64;
        __syncthreads();   // protect LDS from previous iteration's readers
#pragma unroll
        for (int e = 0; e < 8; ++e) {
            int idx = e * 1024 + tid * 4;
            int row = idx >> 7, col = idx & 127;
            *(float4*)&Blds[row][col] =
                *(const float4*)&emb[(size_t)(j0 + row) * DIM + col];
        }
        if (tid < 64) {
            sqj[tid]  = sq[j0 + tid];
            labj[tid] = labels[j0 + tid];
        }
        __syncthreads();

        float acc[4][4] = {};
#pragma unroll
        for (int k4 = 0; k4 < 32; ++k4) {
            float4 a[4], b[4];
#pragma unroll
            for (int r = 0; r < 4; ++r) a[r] = *(float4*)&Alds[ty + 16 * r][k4 * 4];
#pragma unroll
            for (int c = 0; c < 4; ++c) b[c] = *(float4*)&Blds[tx + 16 * c][k4 * 4];
#pragma unroll
            for (int r = 0; r < 4; ++r)
#pragma unroll
                for (int c = 0; c < 4; ++c) {
                    acc[r][c] += a[r].x * b[c].x;
                    acc[r][c] += a[r].y * b[c].y;
                    acc[r][c] += a[r].z * b[c].z;
                    acc[r][c] += a[r].w * b[c].w;
                }
        }

#pragma unroll
        for (int c = 0; c < 4; ++c) {
            const int jj = j0 + tx + 16 * c;
            const float sj = sqj[tx + 16 * c];
            const int   lj = labj[tx + 16 * c];
#pragma unroll
            for (int r = 0; r < 4; ++r) {
                float d2 = sqi[r] + sj - 2.0f * acc[r][c];
                float dist = sqrtf(fmaxf(d2, 0.0f) + EPS);
                if (lj == labi[r]) {
                    if (jj != irow[r]) mp[r] = fmaxf(mp[r], dist);
                } else {
                    mn[r] = fminf(mn[r], dist);
                }
            }
        }
    }

    // reduce across the 16 tx lanes (contiguous within a wave)
#pragma unroll
    for (int m = 1; m < 16; m <<= 1) {
#pragma unroll
        for (int r = 0; r < 4; ++r) {
            mp[r] = fmaxf(mp[r], __shfl_xor(mp[r], m));
            mn[r] = fminf(mn[r], __shfl_xor(mn[r], m));
        }
    }
    if (tx == 0) {
#pragma unroll
        for (int r = 0; r < 4; ++r) {
            atomicMax(&maxp[irow[r]], __float_as_uint(mp[r]));
            atomicMin(&minn[irow[r]], __float_as_uint(mn[r]));
        }
    }
}

__global__ __launch_bounds__(256) void k_final(const unsigned* __restrict__ maxp,
                                               const unsigned* __restrict__ minn,
                                               float* __restrict__ sumcnt) {
    int i = blockIdx.x * 256 + threadIdx.x;
    float mp = __uint_as_float(maxp[i]);
    float mn = __uint_as_float(minn[i]);
    bool valid = (mp > 0.0f) && (mn < __uint_as_float(0x7F800000u));
    float per = valid ? fmaxf(mp - mn + MARGIN, 0.0f) : 0.0f;
    unsigned cnt = valid ? 1u : 0u;
#pragma unroll
    for (int m = 32; m >= 1; m >>= 1) {
        per += __shfl_xor(per, m);
        cnt += __shfl_xor(cnt, m);
    }
    __shared__ float    ssum[4];
    __shared__ unsigned scnt[4];
    int wid = threadIdx.x >> 6;
    if ((threadIdx.x & 63) == 0) { ssum[wid] = per; scnt[wid] = cnt; }
    __syncthreads();
    if (threadIdx.x == 0) {
        float s = ssum[0] + ssum[1] + ssum[2] + ssum[3];
        unsigned c = scnt[0] + scnt[1] + scnt[2] + scnt[3];
        atomicAdd(&sumcnt[0], s);
        atomicAdd((unsigned*)&sumcnt[1], c);
    }
}

__global__ void k_out(const float* __restrict__ sumcnt, float* __restrict__ out) {
    if (threadIdx.x == 0) {
        float s = sumcnt[0];
        unsigned c = ((const unsigned*)sumcnt)[1];
        out[0] = s / (float)(c > 0u ? c : 1u);
    }
}

extern "C" void kernel_launch(void* const* d_in, const int* in_sizes, int n_in,
                              void* d_out, int out_size, void* d_ws, size_t ws_size,
                              hipStream_t stream) {
    const float* emb    = (const float*)d_in[0];
    const int*   labels = (const int*)d_in[1];

    float*    sq     = (float*)d_ws;
    unsigned* maxp   = (unsigned*)d_ws + 8192;
    unsigned* minn   = (unsigned*)d_ws + 16384;
    float*    sumcnt = (float*)d_ws + 24576;
    float*    out    = (float*)d_out;

    k_sqnorm<<<dim3(BSZ / 8), dim3(256), 0, stream>>>(emb, sq, maxp, minn, sumcnt);
    k_main<<<dim3(BSZ / 64, 16), dim3(256), 0, stream>>>(emb, labels, sq, maxp, minn);
    k_final<<<dim3(BSZ / 256), dim3(256), 0, stream>>>(maxp, minn, sumcnt);
    k_out<<<dim3(1), dim3(64), 0, stream>>>(sumcnt, out);
}

// Round 2
// 140.013 us; speedup vs baseline: 69.1945x; 69.1945x over previous
//
#include <hip/hip_runtime.h>

#define BSZ 8192
#define DIM 128
#define MARGIN 0.3f
#define EPS 1e-8f

typedef __bf16 bf16x8 __attribute__((ext_vector_type(8)));
typedef float f32x4 __attribute__((ext_vector_type(4)));

// ws layout:
// [0 .. 1M)            __bf16 hi[8192*128]   (2 MB)
// [1M .. 2M)           __bf16 lo[8192*128]   (2 MB)
// then: float sq[8192]; uint maxp[8192]; uint minn[8192]; {float sum; uint cnt}
// maxp key = relu(d2)+1  (0 = no positive seen)
// minn key = relu(d2)    (+inf = no negative seen)

__global__ __launch_bounds__(256) void k_prep(const float* __restrict__ emb,
                                              __bf16* __restrict__ hi,
                                              __bf16* __restrict__ lo,
                                              float* __restrict__ sq,
                                              unsigned* __restrict__ maxp,
                                              unsigned* __restrict__ minn,
                                              float* __restrict__ sumcnt) {
    int row = blockIdx.x * 4 + (threadIdx.x >> 6);
    int lane = threadIdx.x & 63;
    float2 v = *(const float2*)&emb[(size_t)row * DIM + lane * 2];
    __bf16 h0 = (__bf16)v.x, h1 = (__bf16)v.y;
    __bf16 l0 = (__bf16)(v.x - (float)h0), l1 = (__bf16)(v.y - (float)h1);
    union { __bf16 b[2]; unsigned u; } ph, pl;
    ph.b[0] = h0; ph.b[1] = h1;
    pl.b[0] = l0; pl.b[1] = l1;
    ((unsigned*)hi)[row * 64 + lane] = ph.u;
    ((unsigned*)lo)[row * 64 + lane] = pl.u;
    float s = v.x * v.x + v.y * v.y;
#pragma unroll
    for (int m = 32; m >= 1; m >>= 1) s += __shfl_xor(s, m);
    if (lane == 0) {
        sq[row] = s;
        maxp[row] = 0u;
        minn[row] = 0x7F800000u;
    }
    if (blockIdx.x == 0 && threadIdx.x == 0) {
        sumcnt[0] = 0.0f;
        ((unsigned*)sumcnt)[1] = 0u;
    }
}

// Each wave owns 2 i-tiles (32 anchor rows) and sweeps 32 j-tiles (512 cols).
// MFMA 16x16x32 bf16; split-bf16 (hi+lo) for ~fp32 dot accuracy.
// Fragment mapping (verified layout): lane l, elem e, K-frag f:
//   A[row=l&15][k=32f+8*(l>>4)+e],  B[k=32f+8*(l>>4)+e][col=l&15]
//   C/D: col=lane&15, row=(lane>>4)*4+reg
__global__ __launch_bounds__(256, 2) void k_mfma(const __bf16* __restrict__ hi,
                                                 const __bf16* __restrict__ lo,
                                                 const int* __restrict__ labels,
                                                 const float* __restrict__ sq,
                                                 unsigned* __restrict__ maxp,
                                                 unsigned* __restrict__ minn) {
    const int lane = threadIdx.x & 63;
    const int wave = threadIdx.x >> 6;
    const int lr = lane & 15;
    const int lq = lane >> 4;
    const int it0 = blockIdx.x * 128 + wave * 32;
    const int it1 = it0 + 16;
    const int j0base = blockIdx.y * 512;
    const float INF = __uint_as_float(0x7F800000u);

    bf16x8 a0h[4], a0l[4], a1h[4], a1l[4];
    const size_t ar0 = (size_t)(it0 + lr) * DIM + lq * 8;
    const size_t ar1 = (size_t)(it1 + lr) * DIM + lq * 8;
#pragma unroll
    for (int f = 0; f < 4; ++f) {
        a0h[f] = *(const bf16x8*)&hi[ar0 + f * 32];
        a0l[f] = *(const bf16x8*)&lo[ar0 + f * 32];
        a1h[f] = *(const bf16x8*)&hi[ar1 + f * 32];
        a1l[f] = *(const bf16x8*)&lo[ar1 + f * 32];
    }
    float sqi0[4], sqi1[4];
    int labi0[4], labi1[4];
    bool dmr[4];
#pragma unroll
    for (int r = 0; r < 4; ++r) {
        sqi0[r] = sq[it0 + lq * 4 + r];
        labi0[r] = labels[it0 + lq * 4 + r];
        sqi1[r] = sq[it1 + lq * 4 + r];
        labi1[r] = labels[it1 + lq * 4 + r];
        dmr[r] = (lq * 4 + r) == lr;
    }
    float mp0[4] = {0, 0, 0, 0}, mp1[4] = {0, 0, 0, 0};
    float mn0[4], mn1[4];
#pragma unroll
    for (int r = 0; r < 4; ++r) { mn0[r] = INF; mn1[r] = INF; }

    const __bf16* bh = hi + (size_t)(j0base + lr) * DIM + lq * 8;
    const __bf16* bl = lo + (size_t)(j0base + lr) * DIM + lq * 8;

#pragma unroll 1
    for (int jt = 0; jt < 32; ++jt) {
        const int j0 = j0base + jt * 16;
        bf16x8 bhf[4], blf[4];
#pragma unroll
        for (int f = 0; f < 4; ++f) {
            bhf[f] = *(const bf16x8*)&bh[f * 32];
            blf[f] = *(const bf16x8*)&bl[f * 32];
        }
        bh += 16 * DIM;
        bl += 16 * DIM;

        f32x4 acc0 = {0, 0, 0, 0}, acc1 = {0, 0, 0, 0};
#pragma unroll
        for (int f = 0; f < 4; ++f) {
            acc0 = __builtin_amdgcn_mfma_f32_16x16x32_bf16(a0h[f], bhf[f], acc0, 0, 0, 0);
            acc1 = __builtin_amdgcn_mfma_f32_16x16x32_bf16(a1h[f], bhf[f], acc1, 0, 0, 0);
            acc0 = __builtin_amdgcn_mfma_f32_16x16x32_bf16(a0h[f], blf[f], acc0, 0, 0, 0);
            acc1 = __builtin_amdgcn_mfma_f32_16x16x32_bf16(a1h[f], blf[f], acc1, 0, 0, 0);
            acc0 = __builtin_amdgcn_mfma_f32_16x16x32_bf16(a0l[f], bhf[f], acc0, 0, 0, 0);
            acc1 = __builtin_amdgcn_mfma_f32_16x16x32_bf16(a1l[f], bhf[f], acc1, 0, 0, 0);
        }

        const int jj = j0 + lr;
        const float sqj = sq[jj];
        const int labj = labels[jj];
        const bool tdm0 = (it0 == j0);
        const bool tdm1 = (it1 == j0);
#pragma unroll
        for (int r = 0; r < 4; ++r) {
            {
                float d2 = fmaf(-2.0f, acc0[r], sqi0[r] + sqj);
                float rd2 = fmaxf(d2, 0.0f);
                if (labj == labi0[r]) {
                    if (!(tdm0 && dmr[r])) mp0[r] = fmaxf(mp0[r], rd2 + 1.0f);
                } else {
                    mn0[r] = fminf(mn0[r], rd2);
                }
            }
            {
                float d2 = fmaf(-2.0f, acc1[r], sqi1[r] + sqj);
                float rd2 = fmaxf(d2, 0.0f);
                if (labj == labi1[r]) {
                    if (!(tdm1 && dmr[r])) mp1[r] = fmaxf(mp1[r], rd2 + 1.0f);
                } else {
                    mn1[r] = fminf(mn1[r], rd2);
                }
            }
        }
    }

    // reduce over the 16 cols (lr) within each quad-group
#pragma unroll
    for (int m = 1; m < 16; m <<= 1) {
#pragma unroll
        for (int r = 0; r < 4; ++r) {
            mp0[r] = fmaxf(mp0[r], __shfl_xor(mp0[r], m));
            mn0[r] = fminf(mn0[r], __shfl_xor(mn0[r], m));
            mp1[r] = fmaxf(mp1[r], __shfl_xor(mp1[r], m));
            mn1[r] = fminf(mn1[r], __shfl_xor(mn1[r], m));
        }
    }
    if (lr == 0) {
#pragma unroll
        for (int r = 0; r < 4; ++r) {
            atomicMax(&maxp[it0 + lq * 4 + r], __float_as_uint(mp0[r]));
            atomicMin(&minn[it0 + lq * 4 + r], __float_as_uint(mn0[r]));
            atomicMax(&maxp[it1 + lq * 4 + r], __float_as_uint(mp1[r]));
            atomicMin(&minn[it1 + lq * 4 + r], __float_as_uint(mn1[r]));
        }
    }
}

__global__ __launch_bounds__(256) void k_final(const unsigned* __restrict__ maxp,
                                               const unsigned* __restrict__ minn,
                                               float* __restrict__ sumcnt) {
    int i = blockIdx.x * 256 + threadIdx.x;
    unsigned kp = maxp[i];
    float mnv = __uint_as_float(minn[i]);
    const float INF = __uint_as_float(0x7F800000u);
    bool valid = (kp != 0u) && (mnv < INF);
    float hp = sqrtf((__uint_as_float(kp) - 1.0f) + EPS);
    float hn = sqrtf(mnv + EPS);
    float per = valid ? fmaxf(hp - hn + MARGIN, 0.0f) : 0.0f;
    unsigned cnt = valid ? 1u : 0u;
#pragma unroll
    for (int m = 32; m >= 1; m >>= 1) {
        per += __shfl_xor(per, m);
        cnt += __shfl_xor(cnt, m);
    }
    __shared__ float ssum[4];
    __shared__ unsigned scnt[4];
    int wid = threadIdx.x >> 6;
    if ((threadIdx.x & 63) == 0) { ssum[wid] = per; scnt[wid] = cnt; }
    __syncthreads();
    if (threadIdx.x == 0) {
        float s = ssum[0] + ssum[1] + ssum[2] + ssum[3];
        unsigned c = scnt[0] + scnt[1] + scnt[2] + scnt[3];
        atomicAdd(&sumcnt[0], s);
        atomicAdd((unsigned*)&sumcnt[1], c);
    }
}

__global__ void k_out(const float* __restrict__ sumcnt, float* __restrict__ out) {
    if (threadIdx.x == 0) {
        float s = sumcnt[0];
        unsigned c = ((const unsigned*)sumcnt)[1];
        out[0] = s / (float)(c > 0u ? c : 1u);
    }
}

extern "C" void kernel_launch(void* const* d_in, const int* in_sizes, int n_in,
                              void* d_out, int out_size, void* d_ws, size_t ws_size,
                              hipStream_t stream) {
    const float* emb    = (const float*)d_in[0];
    const int*   labels = (const int*)d_in[1];

    __bf16* hi = (__bf16*)d_ws;
    __bf16* lo = hi + (size_t)BSZ * DIM;
    float*  sq = (float*)(lo + (size_t)BSZ * DIM);
    unsigned* maxp = (unsigned*)(sq + BSZ);
    unsigned* minn = maxp + BSZ;
    float* sumcnt = (float*)(minn + BSZ);
    float* out = (float*)d_out;

    k_prep<<<dim3(BSZ / 4), dim3(256), 0, stream>>>(emb, hi, lo, sq, maxp, minn, sumcnt);
    k_mfma<<<dim3(BSZ / 128, 16), dim3(256), 0, stream>>>(hi, lo, labels, sq, maxp, minn);
    k_final<<<dim3(BSZ / 256), dim3(256), 0, stream>>>(maxp, minn, sumcnt);
    k_out<<<dim3(1), dim3(64), 0, stream>>>(sumcnt, out);
}

// Round 3
// 77.045 us; speedup vs baseline: 125.7467x; 1.8173x over previous
//
#include <hip/hip_runtime.h>

#define BSZ 8192
#define DIM 128
#define MARGIN 0.3f
#define EPS 1e-8f
#define NJ 16              // j-splits
#define JCHUNK 512         // BSZ / NJ
#define NT 32              // JCHUNK / 16 tiles per chunk

typedef __bf16 bf16x8 __attribute__((ext_vector_type(8)));
typedef float f32x4 __attribute__((ext_vector_type(4)));

// order-preserving float <-> uint key (works for negative values)
__device__ __forceinline__ unsigned enc_ord(float f) {
    unsigned u = __float_as_uint(f);
    return (u & 0x80000000u) ? ~u : (u | 0x80000000u);
}
__device__ __forceinline__ float dec_ord(unsigned e) {
    unsigned u = (e & 0x80000000u) ? (e & 0x7FFFFFFFu) : ~e;
    return __uint_as_float(u);
}

// ws layout: __bf16 hi[8192*128]; float sq[8192]; uint maxp[8192]; uint minn[8192];
//            {float sum; uint cnt}
// maxp/minn hold enc_ord(key), key = max/min over j of (sqj - 2*dot(i,j))

__global__ __launch_bounds__(256) void k_prep(const float* __restrict__ emb,
                                              __bf16* __restrict__ hi,
                                              float* __restrict__ sq,
                                              unsigned* __restrict__ maxp,
                                              unsigned* __restrict__ minn,
                                              float* __restrict__ sumcnt) {
    int row = blockIdx.x * 4 + (threadIdx.x >> 6);
    int lane = threadIdx.x & 63;
    float2 v = *(const float2*)&emb[(size_t)row * DIM + lane * 2];
    union { __bf16 b[2]; unsigned u; } p;
    p.b[0] = (__bf16)v.x;
    p.b[1] = (__bf16)v.y;
    ((unsigned*)hi)[row * 64 + lane] = p.u;
    float s = v.x * v.x + v.y * v.y;
#pragma unroll
    for (int m = 32; m >= 1; m >>= 1) s += __shfl_xor(s, m);
    if (lane == 0) {
        sq[row] = s;
        maxp[row] = 0u;            // < enc_ord of any real float
        minn[row] = 0xFFFFFFFFu;   // > enc_ord of any real float
    }
    if (blockIdx.x == 0 && threadIdx.x == 0) {
        sumcnt[0] = 0.0f;
        ((unsigned*)sumcnt)[1] = 0u;
    }
}

__device__ __forceinline__ void phase(const bf16x8 a0[4], const bf16x8 a1[4],
                                      const bf16x8 bc[4], float sqj, int labj,
                                      const int4& li0, const int4& li1,
                                      float mp0[4], float mn0[4],
                                      float mp1[4], float mn1[4]) {
    f32x4 acc0 = {0, 0, 0, 0}, acc1 = {0, 0, 0, 0};
#pragma unroll
    for (int f = 0; f < 4; ++f) {
        acc0 = __builtin_amdgcn_mfma_f32_16x16x32_bf16(a0[f], bc[f], acc0, 0, 0, 0);
        acc1 = __builtin_amdgcn_mfma_f32_16x16x32_bf16(a1[f], bc[f], acc1, 0, 0, 0);
    }
    const int labi0[4] = {li0.x, li0.y, li0.z, li0.w};
    const int labi1[4] = {li1.x, li1.y, li1.z, li1.w};
#pragma unroll
    for (int r = 0; r < 4; ++r) {
        float k0 = fmaf(-2.0f, acc0[r], sqj);
        float k1 = fmaf(-2.0f, acc1[r], sqj);
        bool s0 = (labj == labi0[r]);
        bool s1 = (labj == labi1[r]);
        mp0[r] = s0 ? fmaxf(mp0[r], k0) : mp0[r];
        mn0[r] = s0 ? mn0[r] : fminf(mn0[r], k0);
        mp1[r] = s1 ? fmaxf(mp1[r], k1) : mp1[r];
        mn1[r] = s1 ? mn1[r] : fminf(mn1[r], k1);
    }
}

__global__ __launch_bounds__(256, 4) void k_mfma(const __bf16* __restrict__ hi,
                                                 const int* __restrict__ labels,
                                                 const float* __restrict__ sq,
                                                 unsigned* __restrict__ maxp,
                                                 unsigned* __restrict__ minn) {
    __shared__ float sqlds[JCHUNK];
    __shared__ int lablds[JCHUNK];

    const int tid = threadIdx.x;
    const int lane = tid & 63;
    const int wave = tid >> 6;
    const int lr = lane & 15;
    const int lq = lane >> 4;
    const int i0 = blockIdx.x * 128;
    const int it0 = i0 + wave * 32;
    const int it1 = it0 + 16;
    const int j0 = blockIdx.y * JCHUNK;
    const float INF = __uint_as_float(0x7F800000u);

#pragma unroll
    for (int s = 0; s < JCHUNK / 256; ++s) {
        sqlds[s * 256 + tid] = sq[j0 + s * 256 + tid];
        lablds[s * 256 + tid] = labels[j0 + s * 256 + tid];
    }

    // A fragments: 2 i-tiles x 4 K-frags, register-resident (32 VGPR)
    bf16x8 a0[4], a1[4];
    const __bf16* ap = hi + (size_t)(it0 + lr) * DIM + lq * 8;
#pragma unroll
    for (int f = 0; f < 4; ++f) {
        a0[f] = *(const bf16x8*)&ap[f * 32];
        a1[f] = *(const bf16x8*)&ap[16 * DIM + f * 32];
    }
    const int4 li0 = *(const int4*)&labels[it0 + lq * 4];
    const int4 li1 = *(const int4*)&labels[it1 + lq * 4];

    float mp0[4], mp1[4], mn0[4], mn1[4];
#pragma unroll
    for (int r = 0; r < 4; ++r) {
        mp0[r] = -INF; mp1[r] = -INF;
        mn0[r] = INF;  mn1[r] = INF;
    }

    __syncthreads();

    const __bf16* bbase = hi + (size_t)(j0 + lr) * DIM + lq * 8;
    bf16x8 bA[4], bB[4];
    float sqjA, sqjB;
    int labjA, labjB;
#pragma unroll
    for (int f = 0; f < 4; ++f) bA[f] = *(const bf16x8*)&bbase[f * 32];
    sqjA = sqlds[lr];
    labjA = lablds[lr];

#pragma unroll 1
    for (int jp = 0; jp < NT / 2; ++jp) {
        {   // tile 2jp (bA current); prefetch 2jp+1 -> bB
            const __bf16* bp = bbase + (size_t)(2 * jp + 1) * 16 * DIM;
#pragma unroll
            for (int f = 0; f < 4; ++f) bB[f] = *(const bf16x8*)&bp[f * 32];
            sqjB = sqlds[(2 * jp + 1) * 16 + lr];
            labjB = lablds[(2 * jp + 1) * 16 + lr];
            phase(a0, a1, bA, sqjA, labjA, li0, li1, mp0, mn0, mp1, mn1);
        }
        {   // tile 2jp+1 (bB current); prefetch (2jp+2)&31 -> bA (wraps, in-bounds)
            const int nt = (2 * jp + 2) & (NT - 1);
            const __bf16* bp = bbase + (size_t)nt * 16 * DIM;
#pragma unroll
            for (int f = 0; f < 4; ++f) bA[f] = *(const bf16x8*)&bp[f * 32];
            sqjA = sqlds[nt * 16 + lr];
            labjA = lablds[nt * 16 + lr];
            phase(a0, a1, bB, sqjB, labjB, li0, li1, mp0, mn0, mp1, mn1);
        }
    }

    // reduce across the 16 cols (lr) within each lq quarter
#pragma unroll
    for (int m = 1; m < 16; m <<= 1) {
#pragma unroll
        for (int r = 0; r < 4; ++r) {
            mp0[r] = fmaxf(mp0[r], __shfl_xor(mp0[r], m));
            mn0[r] = fminf(mn0[r], __shfl_xor(mn0[r], m));
            mp1[r] = fmaxf(mp1[r], __shfl_xor(mp1[r], m));
            mn1[r] = fminf(mn1[r], __shfl_xor(mn1[r], m));
        }
    }
    if (lr == 0) {
#pragma unroll
        for (int r = 0; r < 4; ++r) {
            atomicMax(&maxp[it0 + lq * 4 + r], enc_ord(mp0[r]));
            atomicMin(&minn[it0 + lq * 4 + r], enc_ord(mn0[r]));
            atomicMax(&maxp[it1 + lq * 4 + r], enc_ord(mp1[r]));
            atomicMin(&minn[it1 + lq * 4 + r], enc_ord(mn1[r]));
        }
    }
}

__global__ __launch_bounds__(256) void k_final(const unsigned* __restrict__ maxp,
                                               const unsigned* __restrict__ minn,
                                               const float* __restrict__ sq,
                                               float* __restrict__ sumcnt) {
    int i = blockIdx.x * 256 + threadIdx.x;
    float mpd = dec_ord(maxp[i]);
    float mnd = dec_ord(minn[i]);
    float sqi = sq[i];
    bool valid = (mpd > -1e30f) && (mnd < 1e30f);
    float hp = sqrtf(fmaxf(sqi + mpd, 0.0f) + EPS);
    float hn = sqrtf(fmaxf(sqi + mnd, 0.0f) + EPS);
    float per = valid ? fmaxf(hp - hn + MARGIN, 0.0f) : 0.0f;
    unsigned cnt = valid ? 1u : 0u;
#pragma unroll
    for (int m = 32; m >= 1; m >>= 1) {
        per += __shfl_xor(per, m);
        cnt += __shfl_xor(cnt, m);
    }
    __shared__ float ssum[4];
    __shared__ unsigned scnt[4];
    int wid = threadIdx.x >> 6;
    if ((threadIdx.x & 63) == 0) { ssum[wid] = per; scnt[wid] = cnt; }
    __syncthreads();
    if (threadIdx.x == 0) {
        float s = ssum[0] + ssum[1] + ssum[2] + ssum[3];
        unsigned c = scnt[0] + scnt[1] + scnt[2] + scnt[3];
        atomicAdd(&sumcnt[0], s);
        atomicAdd((unsigned*)&sumcnt[1], c);
    }
}

__global__ void k_out(const float* __restrict__ sumcnt, float* __restrict__ out) {
    if (threadIdx.x == 0) {
        float s = sumcnt[0];
        unsigned c = ((const unsigned*)sumcnt)[1];
        out[0] = s / (float)(c > 0u ? c : 1u);
    }
}

extern "C" void kernel_launch(void* const* d_in, const int* in_sizes, int n_in,
                              void* d_out, int out_size, void* d_ws, size_t ws_size,
                              hipStream_t stream) {
    const float* emb    = (const float*)d_in[0];
    const int*   labels = (const int*)d_in[1];

    __bf16* hi = (__bf16*)d_ws;
    float*  sq = (float*)(hi + (size_t)BSZ * DIM);
    unsigned* maxp = (unsigned*)(sq + BSZ);
    unsigned* minn = maxp + BSZ;
    float* sumcnt = (float*)(minn + BSZ);
    float* out = (float*)d_out;

    k_prep<<<dim3(BSZ / 4), dim3(256), 0, stream>>>(emb, hi, sq, maxp, minn, sumcnt);
    k_mfma<<<dim3(BSZ / 128, NJ), dim3(256), 0, stream>>>(hi, labels, sq, maxp, minn);
    k_final<<<dim3(BSZ / 256), dim3(256), 0, stream>>>(maxp, minn, sq, sumcnt);
    k_out<<<dim3(1), dim3(64), 0, stream>>>(sumcnt, out);
}

// Round 4
// 46.619 us; speedup vs baseline: 207.8169x; 1.6527x over previous
//
#include <hip/hip_runtime.h>

#define BSZ 8192
#define DIM 128
#define MARGIN 0.3f
#define EPS 1e-8f
#define NJ 16              // j-splits
#define JCHUNK 512         // BSZ / NJ
#define NT 32              // JCHUNK / 16 tiles per chunk

typedef __bf16 bf16x8 __attribute__((ext_vector_type(8)));
typedef float f32x4 __attribute__((ext_vector_type(4)));

// order-preserving float <-> uint key (works for negative values)
__device__ __forceinline__ unsigned enc_ord(float f) {
    unsigned u = __float_as_uint(f);
    return (u & 0x80000000u) ? ~u : (u | 0x80000000u);
}
__device__ __forceinline__ float dec_ord(unsigned e) {
    unsigned u = (e & 0x80000000u) ? (e & 0x7FFFFFFFu) : ~e;
    return __uint_as_float(u);
}

// ws layout: __bf16 hi[8192*128]; float sq[8192]; uint maxp[8192]; uint minn[8192];
//            {float sum; uint cnt}
// maxp/minn hold enc_ord(key), key = max/min over j of (sqj - 2*dot(i,j))

__global__ __launch_bounds__(256) void k_prep(const float* __restrict__ emb,
                                              __bf16* __restrict__ hi,
                                              float* __restrict__ sq,
                                              unsigned* __restrict__ maxp,
                                              unsigned* __restrict__ minn,
                                              float* __restrict__ sumcnt) {
    int row = blockIdx.x * 4 + (threadIdx.x >> 6);
    int lane = threadIdx.x & 63;
    float2 v = *(const float2*)&emb[(size_t)row * DIM + lane * 2];
    union { __bf16 b[2]; unsigned u; } p;
    p.b[0] = (__bf16)v.x;
    p.b[1] = (__bf16)v.y;
    ((unsigned*)hi)[row * 64 + lane] = p.u;
    float s = v.x * v.x + v.y * v.y;
#pragma unroll
    for (int m = 32; m >= 1; m >>= 1) s += __shfl_xor(s, m);
    if (lane == 0) {
        sq[row] = s;
        maxp[row] = 0u;            // < enc_ord of any real float
        minn[row] = 0xFFFFFFFFu;   // > enc_ord of any real float
    }
    if (blockIdx.x == 0 && threadIdx.x == 0) {
        sumcnt[0] = 0.0f;
        ((unsigned*)sumcnt)[1] = 0u;
    }
}

// Block: 256 threads = 4 waves, covers 128 anchor rows (2 x 16-row tiles per wave).
// B tiles (16 cols x K=128) staged in LDS double-buffer via global_load_lds,
// pre-swizzled into exact MFMA B-fragment order; shared by all 4 waves.
__global__ __launch_bounds__(256, 4) void k_mfma(const __bf16* __restrict__ hi,
                                                 const int* __restrict__ labels,
                                                 const float* __restrict__ sq,
                                                 unsigned* __restrict__ maxp,
                                                 unsigned* __restrict__ minn) {
    __shared__ char Bst[2][4][1024];   // [buf][frag][lane*16B]
    __shared__ float sqlds[JCHUNK];
    __shared__ int lablds[JCHUNK];

    const int tid = threadIdx.x;
    const int lane = tid & 63;
    const int wave = tid >> 6;
    const int lr = lane & 15;
    const int lq = lane >> 4;
    const int it0 = blockIdx.x * 128 + wave * 32;
    const int it1 = it0 + 16;
    const int j0 = blockIdx.y * JCHUNK;
    const float INF = __uint_as_float(0x7F800000u);

#pragma unroll
    for (int s = 0; s < JCHUNK / 256; ++s) {
        sqlds[s * 256 + tid] = sq[j0 + s * 256 + tid];
        lablds[s * 256 + tid] = labels[j0 + s * 256 + tid];
    }

    // A fragments: 2 i-tiles x 4 K-frags, register-resident (32 VGPR), pinned
    bf16x8 a0[4], a1[4];
    const __bf16* ap = hi + (size_t)(it0 + lr) * DIM + lq * 8;
#pragma unroll
    for (int f = 0; f < 4; ++f) {
        a0[f] = *(const bf16x8*)&ap[f * 32];
        a1[f] = *(const bf16x8*)&ap[16 * DIM + f * 32];
        asm volatile("" : "+v"(a0[f]));
        asm volatile("" : "+v"(a1[f]));
    }
    const int4 li0 = *(const int4*)&labels[it0 + lq * 4];
    const int4 li1 = *(const int4*)&labels[it1 + lq * 4];
    const int labi0[4] = {li0.x, li0.y, li0.z, li0.w};
    const int labi1[4] = {li1.x, li1.y, li1.z, li1.w};

    float mp0[4], mp1[4], mn0[4], mn1[4];
#pragma unroll
    for (int r = 0; r < 4; ++r) {
        mp0[r] = -INF; mp1[r] = -INF;
        mn0[r] = INF;  mn1[r] = INF;
    }

    // stage: wave w loads K-frag w of j-tile jt into Bst[buf][w][lane*16].
    // src per-lane: emb_bf16[j0 + jt*16 + (lane&15)][w*32 + (lane>>4)*8 .. +8]
    const __bf16* bsrc0 = hi + (size_t)(j0 + lr) * DIM + lq * 8 + wave * 32;
#define STAGE(jt, buf)                                                               \
    __builtin_amdgcn_global_load_lds(                                                \
        (const __attribute__((address_space(1))) void*)(bsrc0 + (size_t)(jt) * 16 * DIM), \
        (__attribute__((address_space(3))) void*)&Bst[buf][wave][0], 16, 0, 0)

    STAGE(0, 0);
    __syncthreads();   // drains global_load_lds (vmcnt) + sq/lab ds_writes

#pragma unroll 1
    for (int t = 0; t < NT; ++t) {
        if (t + 1 < NT) STAGE(t + 1, (t + 1) & 1);

        const float sqj = sqlds[t * 16 + lr];
        const int labj = lablds[t * 16 + lr];

        const bf16x8* bp = (const bf16x8*)&Bst[t & 1][0][0];
        f32x4 acc0 = {0, 0, 0, 0}, acc1 = {0, 0, 0, 0};
#pragma unroll
        for (int f = 0; f < 4; ++f) {
            bf16x8 b = bp[f * 64 + lane];
            acc0 = __builtin_amdgcn_mfma_f32_16x16x32_bf16(a0[f], b, acc0, 0, 0, 0);
            acc1 = __builtin_amdgcn_mfma_f32_16x16x32_bf16(a1[f], b, acc1, 0, 0, 0);
        }

#pragma unroll
        for (int r = 0; r < 4; ++r) {
            float k0 = fmaf(-2.0f, acc0[r], sqj);
            float k1 = fmaf(-2.0f, acc1[r], sqj);
            bool s0 = (labj == labi0[r]);
            bool s1 = (labj == labi1[r]);
            mp0[r] = s0 ? fmaxf(mp0[r], k0) : mp0[r];
            mn0[r] = s0 ? mn0[r] : fminf(mn0[r], k0);
            mp1[r] = s1 ? fmaxf(mp1[r], k1) : mp1[r];
            mn1[r] = s1 ? mn1[r] : fminf(mn1[r], k1);
        }

        __syncthreads();   // auto vmcnt(0): next buffer staged; LDS safe to reuse
    }
#undef STAGE

    // reduce across the 16 cols (lr) within each lq quarter
#pragma unroll
    for (int m = 1; m < 16; m <<= 1) {
#pragma unroll
        for (int r = 0; r < 4; ++r) {
            mp0[r] = fmaxf(mp0[r], __shfl_xor(mp0[r], m));
            mn0[r] = fminf(mn0[r], __shfl_xor(mn0[r], m));
            mp1[r] = fmaxf(mp1[r], __shfl_xor(mp1[r], m));
            mn1[r] = fminf(mn1[r], __shfl_xor(mn1[r], m));
        }
    }
    if (lr == 0) {
#pragma unroll
        for (int r = 0; r < 4; ++r) {
            atomicMax(&maxp[it0 + lq * 4 + r], enc_ord(mp0[r]));
            atomicMin(&minn[it0 + lq * 4 + r], enc_ord(mn0[r]));
            atomicMax(&maxp[it1 + lq * 4 + r], enc_ord(mp1[r]));
            atomicMin(&minn[it1 + lq * 4 + r], enc_ord(mn1[r]));
        }
    }
}

__global__ __launch_bounds__(256) void k_final(const unsigned* __restrict__ maxp,
                                               const unsigned* __restrict__ minn,
                                               const float* __restrict__ sq,
                                               float* __restrict__ sumcnt) {
    int i = blockIdx.x * 256 + threadIdx.x;
    float mpd = dec_ord(maxp[i]);
    float mnd = dec_ord(minn[i]);
    float sqi = sq[i];
    bool valid = (mpd > -1e30f) && (mnd < 1e30f);
    float hp = sqrtf(fmaxf(sqi + mpd, 0.0f) + EPS);
    float hn = sqrtf(fmaxf(sqi + mnd, 0.0f) + EPS);
    float per = valid ? fmaxf(hp - hn + MARGIN, 0.0f) : 0.0f;
    unsigned cnt = valid ? 1u : 0u;
#pragma unroll
    for (int m = 32; m >= 1; m >>= 1) {
        per += __shfl_xor(per, m);
        cnt += __shfl_xor(cnt, m);
    }
    __shared__ float ssum[4];
    __shared__ unsigned scnt[4];
    int wid = threadIdx.x >> 6;
    if ((threadIdx.x & 63) == 0) { ssum[wid] = per; scnt[wid] = cnt; }
    __syncthreads();
    if (threadIdx.x == 0) {
        float s = ssum[0] + ssum[1] + ssum[2] + ssum[3];
        unsigned c = scnt[0] + scnt[1] + scnt[2] + scnt[3];
        atomicAdd(&sumcnt[0], s);
        atomicAdd((unsigned*)&sumcnt[1], c);
    }
}

__global__ void k_out(const float* __restrict__ sumcnt, float* __restrict__ out) {
    if (threadIdx.x == 0) {
        float s = sumcnt[0];
        unsigned c = ((const unsigned*)sumcnt)[1];
        out[0] = s / (float)(c > 0u ? c : 1u);
    }
}

extern "C" void kernel_launch(void* const* d_in, const int* in_sizes, int n_in,
                              void* d_out, int out_size, void* d_ws, size_t ws_size,
                              hipStream_t stream) {
    const float* emb    = (const float*)d_in[0];
    const int*   labels = (const int*)d_in[1];

    __bf16* hi = (__bf16*)d_ws;
    float*  sq = (float*)(hi + (size_t)BSZ * DIM);
    unsigned* maxp = (unsigned*)(sq + BSZ);
    unsigned* minn = maxp + BSZ;
    float* sumcnt = (float*)(minn + BSZ);
    float* out = (float*)d_out;

    k_prep<<<dim3(BSZ / 4), dim3(256), 0, stream>>>(emb, hi, sq, maxp, minn, sumcnt);
    k_mfma<<<dim3(BSZ / 128, NJ), dim3(256), 0, stream>>>(hi, labels, sq, maxp, minn);
    k_final<<<dim3(BSZ / 256), dim3(256), 0, stream>>>(maxp, minn, sq, sumcnt);
    k_out<<<dim3(1), dim3(64), 0, stream>>>(sumcnt, out);
}